// Round 12
// baseline (1681.326 us; speedup 1.0000x reference)
//
#include <hip/hip_runtime.h>

#define BB 32
#define TT 2048
#define DD 256
#define HH 256
#define AA 128
#define CC 4367
#define CLS_LD 4480   // 35*128, padded WclsT leading dim
#define NSTEPS 22
#define NCHUNK 32     // att t-chunks (64 t each)

typedef unsigned short ushortT;
typedef unsigned int uintT;
typedef unsigned long long u64T;
using frag8 = __attribute__((ext_vector_type(8))) short;
using f32x4 = __attribute__((ext_vector_type(4))) float;

__device__ __forceinline__ float tanh_fast(float u) {
  float e = __expf(2.0f * u);
  return 1.0f - 2.0f / (e + 1.0f);
}
__device__ __forceinline__ float sigmoid_fast(float u) {
  return 1.0f / (1.0f + __expf(-u));
}
__device__ __forceinline__ ushortT f2bf(float f) {
  unsigned int u = __float_as_uint(f);
  unsigned int r = (u + 0x7FFFu + ((u >> 16) & 1u)) >> 16;
  return (ushortT)r;
}
__device__ __forceinline__ float bf2f(ushortT v) {
  return __uint_as_float(((unsigned int)v) << 16);
}

// ---------- prep: WclsT fp32 [256][4480] and WxT_bf bf16 [128][256] ----------
__global__ __launch_bounds__(256) void trans_kernel(
    const float* __restrict__ Wx, const float* __restrict__ W_cls,
    float* __restrict__ WclsT, ushortT* __restrict__ WxT_bf) {
  int blk = blockIdx.x;
  __shared__ float tile[32][33];
  const int li = threadIdx.x >> 5, lj = threadIdx.x & 31;
  if (blk < 1096) {  // W_cls 4367x256 -> WclsT 256x4480
    int i0 = (blk >> 3) * 32, j0 = (blk & 7) * 32;
#pragma unroll
    for (int k = 0; k < 4; ++k) {
      int i = i0 + li + k * 8;
      if (i < CC) tile[li + k * 8][lj] = W_cls[(size_t)i * 256 + j0 + lj];
    }
    __syncthreads();
#pragma unroll
    for (int k = 0; k < 4; ++k) {
      int j = j0 + li + k * 8, i = i0 + lj;
      if (i < CC) WclsT[(size_t)j * CLS_LD + i] = tile[lj][li + k * 8];
    }
  } else {  // Wx 256x128 -> WxT_bf 128x256
    blk -= 1096;  // 0..31
    int i0 = (blk >> 2) * 32, j0 = (blk & 3) * 32;
#pragma unroll
    for (int k = 0; k < 4; ++k)
      tile[li + k * 8][lj] = Wx[(size_t)(i0 + li + k * 8) * 128 + j0 + lj];
    __syncthreads();
#pragma unroll
    for (int k = 0; k < 4; ++k) {
      int j = j0 + li + k * 8;
      WxT_bf[(size_t)j * 256 + i0 + lj] = f2bf(tile[lj][li + k * 8]);
    }
  }
}

// ---------- xW via MFMA bf16: block = 128 rows of [BT,256] x [256,128] ----------
__global__ __launch_bounds__(256) void xw_mfma(
    const float* __restrict__ x, const ushortT* __restrict__ WxT_bf,
    ushortT* __restrict__ x_bf, ushortT* __restrict__ xWT) {
  __shared__ ushortT lds[2 * 128 * 72];  // sX | sW staging; reused as sT[128][136]
#define SX(r, c) lds[(r) * 72 + (c)]
#define SW(r, c) lds[128 * 72 + (r) * 72 + (c)]
#define ST(a, m) lds[(a) * 136 + (m)]
  const int tid = threadIdx.x;
  const int lane = tid & 63, w = tid >> 6;
  const int l15 = lane & 15, quad = lane >> 4;
  const int r0 = blockIdx.x * 128;
  const int bb = blockIdx.x >> 4, t0 = (blockIdx.x & 15) * 128;
  const int row = tid >> 1, half = tid & 1;

  f32x4 acc[2][8];
#pragma unroll
  for (int mt = 0; mt < 2; ++mt)
#pragma unroll
    for (int nt = 0; nt < 8; ++nt) acc[mt][nt] = (f32x4){0.f, 0.f, 0.f, 0.f};

  for (int kk0 = 0; kk0 < 256; kk0 += 64) {
    // stage x (fp32 -> bf16) + write-through to x_bf
    {
      const float4* xp = (const float4*)(x + (size_t)(r0 + row) * DD + kk0 + half * 32);
      uint4 pk[4];
#pragma unroll
      for (int i = 0; i < 4; ++i) {
        float4 f0 = xp[2 * i], f1 = xp[2 * i + 1];
        pk[i].x = (uintT)f2bf(f0.x) | ((uintT)f2bf(f0.y) << 16);
        pk[i].y = (uintT)f2bf(f0.z) | ((uintT)f2bf(f0.w) << 16);
        pk[i].z = (uintT)f2bf(f1.x) | ((uintT)f2bf(f1.y) << 16);
        pk[i].w = (uintT)f2bf(f1.z) | ((uintT)f2bf(f1.w) << 16);
      }
      uint4* sxp = (uint4*)&SX(row, half * 32);
      uint4* gxp = (uint4*)(x_bf + (size_t)(r0 + row) * DD + kk0 + half * 32);
#pragma unroll
      for (int i = 0; i < 4; ++i) { sxp[i] = pk[i]; gxp[i] = pk[i]; }
    }
    // stage WxT_bf slice (n=row)
    {
      const uint4* wp = (const uint4*)(WxT_bf + (size_t)row * DD + kk0 + half * 32);
      uint4* swp = (uint4*)&SW(row, half * 32);
#pragma unroll
      for (int i = 0; i < 4; ++i) swp[i] = wp[i];
    }
    __syncthreads();
#pragma unroll
    for (int kk = 0; kk < 2; ++kk) {
      frag8 a0 = *(const frag8*)&SX(w * 32 + l15, kk * 32 + quad * 8);
      frag8 a1 = *(const frag8*)&SX(w * 32 + 16 + l15, kk * 32 + quad * 8);
#pragma unroll
      for (int nt = 0; nt < 8; ++nt) {
        frag8 bf = *(const frag8*)&SW(nt * 16 + l15, kk * 32 + quad * 8);
        acc[0][nt] = __builtin_amdgcn_mfma_f32_16x16x32_bf16(a0, bf, acc[0][nt], 0, 0, 0);
        acc[1][nt] = __builtin_amdgcn_mfma_f32_16x16x32_bf16(a1, bf, acc[1][nt], 0, 0, 0);
      }
    }
    __syncthreads();
  }
  // transpose-bounce: sT[a][m] = D[m][a], then write xWT[b][a][t0+m]
#pragma unroll
  for (int mt = 0; mt < 2; ++mt)
#pragma unroll
    for (int nt = 0; nt < 8; ++nt)
#pragma unroll
      for (int r = 0; r < 4; ++r) {
        int m = w * 32 + mt * 16 + quad * 4 + r;
        int a = nt * 16 + l15;
        ST(a, m) = f2bf(acc[mt][nt][r]);
      }
  __syncthreads();
  {
    const uint4* sp = (const uint4*)&ST(row, half * 64);
    uint4* gp = (uint4*)(xWT + ((size_t)bb * AA + row) * TT + t0 + half * 64);
#pragma unroll
    for (int i = 0; i < 8; ++i) gp[i] = sp[i];
  }
#undef SX
#undef SW
#undef ST
}

// ---------- gates + fused tail h-combine/hWh ----------
// grid (16 slices of 48 gates, 32 b), 256 thr. Gates part is r8/r11-exact.
// NEW: after gi/gh writes, each block does threadfence + agent atomicAdd on
// g_cnt[b]; the 16th arrival (per-b tail block — pattern verified correct in
// round 5) acquires and computes h-combine + hWh in-block, replacing the
// hcomb dispatch (3 kernels/step -> 2; saves 21 launches + gaps). Counter is
// monotonic (16/step/b); memset once per kernel_launch.
__global__ __launch_bounds__(256) void gates_kernel(
    const float* __restrict__ ctx_part, const float* __restrict__ den_part,
    const float* __restrict__ hall_c, const float* __restrict__ W_ih,
    const float* __restrict__ W_hh, const float* __restrict__ b_ih,
    const float* __restrict__ b_hh, const float* __restrict__ Wh,
    float* __restrict__ gi_buf, float* __restrict__ gh_buf,
    float* __restrict__ hall, float* __restrict__ hWh_buf,
    uintT* __restrict__ g_cnt, int s) {
  const int slice = blockIdx.x, b = blockIdx.y, tid = threadIdx.x;
  __shared__ __align__(16) float sctx[DD];
  __shared__ float sden;
  __shared__ float sh[HH];
  __shared__ float part[2][AA];
  __shared__ int sflag;
  if (tid < 32) {  // reduce den partials (one wave)
    float d = den_part[b * NCHUNK + tid];
#pragma unroll
    for (int off = 16; off > 0; off >>= 1) d += __shfl_down(d, off, 32);
    if (tid == 0) sden = d;
  }
  {  // reduce ctx partials: coalesced (256 lanes x 32 chunks)
    float acc = 0.f;
#pragma unroll
    for (int c = 0; c < NCHUNK; ++c)
      acc += ctx_part[((size_t)b * NCHUNK + c) * DD + tid];
    sctx[tid] = acc;
  }
  __syncthreads();
  const float invd = 1.0f / sden;
  const int kq = tid & 15, gsub = tid >> 4;  // gsub 0..15
  const float4* cp = (const float4*)sctx + kq * 4;
  const float4* hrow = (s >= 2) ? (const float4*)(hall_c + ((size_t)(s - 2) * BB + b) * HH) + kq * 4 : nullptr;
  float4 c4[4], h4[4];
#pragma unroll
  for (int j = 0; j < 4; ++j) {
    float4 cv = cp[j];
    c4[j].x = cv.x * invd; c4[j].y = cv.y * invd; c4[j].z = cv.z * invd; c4[j].w = cv.w * invd;
    if (hrow) h4[j] = hrow[j];
    else { h4[j].x = 0.f; h4[j].y = 0.f; h4[j].z = 0.f; h4[j].w = 0.f; }
  }
#pragma unroll
  for (int it = 0; it < 3; ++it) {
    const int g = slice * 48 + it * 16 + gsub;
    const float4* wi = (const float4*)(W_ih + (size_t)g * DD) + kq * 4;
    const float4* wh = (const float4*)(W_hh + (size_t)g * HH) + kq * 4;
    float gi = 0.f, gh = 0.f;
#pragma unroll
    for (int j = 0; j < 4; ++j) {
      float4 wv = wi[j];
      gi += c4[j].x * wv.x + c4[j].y * wv.y + c4[j].z * wv.z + c4[j].w * wv.w;
      wv = wh[j];
      gh += h4[j].x * wv.x + h4[j].y * wv.y + h4[j].z * wv.z + h4[j].w * wv.w;
    }
#pragma unroll
    for (int off = 8; off > 0; off >>= 1) {
      gi += __shfl_down(gi, off, 16);
      gh += __shfl_down(gh, off, 16);
    }
    if (kq == 0) {
      gi_buf[b * 768 + g] = gi + b_ih[g];
      gh_buf[b * 768 + g] = gh + b_hh[g];
    }
  }
  // ---- tail: 16th arrival per b does h-combine + hWh ----
  __threadfence();   // release this block's gi/gh writes
  __syncthreads();
  if (tid == 0) {
    uintT old = __hip_atomic_fetch_add(&g_cnt[b], 1u, __ATOMIC_ACQ_REL,
                                       __HIP_MEMORY_SCOPE_AGENT);
    sflag = ((old & 15u) == 15u) ? 1 : 0;
  }
  __syncthreads();
  if (sflag) {
    __threadfence();  // acquire all slices' gi/gh
    float gir = gi_buf[b * 768 + tid];
    float giz = gi_buf[b * 768 + 256 + tid];
    float gin = gi_buf[b * 768 + 512 + tid];
    float ghr = gh_buf[b * 768 + tid];
    float ghz = gh_buf[b * 768 + 256 + tid];
    float ghn = gh_buf[b * 768 + 512 + tid];
    float hp = (s >= 2) ? hall_c[((size_t)(s - 2) * BB + b) * HH + tid] : 0.f;
    float r = sigmoid_fast(gir + ghr);
    float z = sigmoid_fast(giz + ghz);
    float n = tanh_fast(gin + r * ghn);
    float hv = (1.f - z) * n + z * hp;
    hall[((size_t)(s - 1) * BB + b) * HH + tid] = hv;
    sh[tid] = hv;
    __syncthreads();
    {
      const int a = tid & 127, kh = tid >> 7;
      float acc = 0.f;
#pragma unroll 8
      for (int k = kh * 128; k < kh * 128 + 128; ++k)
        acc = fmaf(sh[k], Wh[k * AA + a], acc);
      part[kh][a] = acc;
    }
    __syncthreads();
    if (tid < AA) hWh_buf[b * AA + tid] = part[0][tid] + part[1][tid];
  }
}

// ---------- per-step attention (r11-exact). grid (32 b, 32 chunks), 256 thr ----------
__global__ __launch_bounds__(256, 4) void att_kernel(
    const ushortT* __restrict__ x_bf, const ushortT* __restrict__ xWT_bf,
    const float* __restrict__ hWh_buf, const float* __restrict__ v,
    float* __restrict__ ctx_part, float* __restrict__ den_part) {
  const int tid = threadIdx.x;
  const int b = blockIdx.x;
  const int chunk = blockIdx.y;  // 0..31, 64 t's each
  const int t0 = chunk * 64;
  __shared__ float sh_hWh[AA], sh_v[AA];
  __shared__ float sh_part[8 * 64];
  __shared__ float sh_w[64];
  __shared__ __align__(16) float sh_ctx[4 * DD];
  if (tid < AA) {
    sh_hWh[tid] = hWh_buf ? hWh_buf[b * AA + tid] : 0.f;
    sh_v[tid] = v[tid];
  }
  __syncthreads();  // waits only the 128-lane LDS stores above
  // x prefetch issues HERE: overlaps with all of Phase A (r11 win: -2.5us/step)
  const int j4 = tid >> 6, dq = tid & 63;
  u64T xr[16];
  {
    const u64T* xb4 = (const u64T*)x_bf;
#pragma unroll
    for (int j = 0; j < 16; ++j)
      xr[j] = __builtin_nontemporal_load(
          &xb4[(((size_t)(b * TT + t0 + j * 4 + j4)) * DD >> 2) + dq]);
  }
  // Phase A: scores. thread = (q = a-group of 16, tp = t-pair)
  {
    const int q = tid >> 5, tp = tid & 31;
    float p0 = 0.f, p1 = 0.f;
    const ushort2* xw2 = (const ushort2*)xWT_bf;
    const size_t base = (size_t)b * (AA * TT / 2) + (t0 >> 1) + tp;
#pragma unroll
    for (int i = 0; i < 16; ++i) {
      int a = q * 16 + i;
      ushort2 u = xw2[base + (size_t)a * (TT / 2)];
      float hwa = sh_hWh[a], va = sh_v[a];
      p0 = fmaf(tanh_fast(bf2f(u.x) + hwa), va, p0);
      p1 = fmaf(tanh_fast(bf2f(u.y) + hwa), va, p1);
    }
    sh_part[q * 64 + 2 * tp] = p0;
    sh_part[q * 64 + 2 * tp + 1] = p1;
  }
  __syncthreads();
  if (tid < 64) {
    float e = 0.f;
#pragma unroll
    for (int q = 0; q < 8; ++q) e += sh_part[q * 64 + tid];
    sh_w[tid] = __expf(e);  // |e| <= ||v||_1 ~ 5: no overflow, no max-pass
  }
  __syncthreads();
  // Phase B: ctx partials from prefetched regs (unpack u64 -> 4 bf16)
  {
    float4 acc = {0.f, 0.f, 0.f, 0.f};
#pragma unroll
    for (int j = 0; j < 16; ++j) {
      float w = sh_w[j * 4 + j4];
      u64T u = xr[j];
      acc.x = fmaf(w, bf2f((ushortT)(u       & 0xFFFFu)), acc.x);
      acc.y = fmaf(w, bf2f((ushortT)((u >> 16) & 0xFFFFu)), acc.y);
      acc.z = fmaf(w, bf2f((ushortT)((u >> 32) & 0xFFFFu)), acc.z);
      acc.w = fmaf(w, bf2f((ushortT)((u >> 48) & 0xFFFFu)), acc.w);
    }
    ((float4*)sh_ctx)[j4 * 64 + dq] = acc;
  }
  __syncthreads();
  {
    float sum = sh_ctx[tid] + sh_ctx[DD + tid] + sh_ctx[2 * DD + tid] + sh_ctx[3 * DD + tid];
    ctx_part[((size_t)b * NCHUNK + chunk) * DD + tid] = sum;  // plain coalesced store
  }
  if (tid < 64) {
    float ds = sh_w[tid];
#pragma unroll
    for (int off = 32; off > 0; off >>= 1) ds += __shfl_down(ds, off, 64);
    if (tid == 0) den_part[b * NCHUNK + chunk] = ds;
  }
}

// ---------- final: out[b,s,c] = hall[s,b,:] @ W_cls^T + b_cls ----------
// r1-EXACT (measured 45.0 us — best of 5 variants; cls frozen).
__global__ __launch_bounds__(256) void cls_kernel(
    const float* __restrict__ hall, const float* __restrict__ WclsT,
    const float* __restrict__ b_cls, float* __restrict__ out) {
  const int tid = threadIdx.x;
  const int c0 = blockIdx.x * 128;
  const int r0 = blockIdx.y * 32;
  const int cq = tid & 31, rg = tid >> 5;
  const int c = c0 + cq * 4;
  __shared__ __align__(16) float shh[32 * HH];
  {
    const float4* hsrc = (const float4*)(hall + (size_t)r0 * HH);
    float4* hdst = (float4*)shh;
#pragma unroll
    for (int i = 0; i < 8; ++i) hdst[tid + 256 * i] = hsrc[tid + 256 * i];
  }
  __syncthreads();
  float acc[4][4];
#pragma unroll
  for (int j = 0; j < 4; ++j)
#pragma unroll
    for (int l = 0; l < 4; ++l) acc[j][l] = 0.f;
#pragma unroll 4
  for (int k = 0; k < HH; ++k) {
    float4 w4 = *(const float4*)(WclsT + (size_t)k * CLS_LD + c);
    float h0 = shh[(rg * 4 + 0) * HH + k];
    float h1 = shh[(rg * 4 + 1) * HH + k];
    float h2 = shh[(rg * 4 + 2) * HH + k];
    float h3 = shh[(rg * 4 + 3) * HH + k];
    acc[0][0] = fmaf(h0, w4.x, acc[0][0]); acc[0][1] = fmaf(h0, w4.y, acc[0][1]);
    acc[0][2] = fmaf(h0, w4.z, acc[0][2]); acc[0][3] = fmaf(h0, w4.w, acc[0][3]);
    acc[1][0] = fmaf(h1, w4.x, acc[1][0]); acc[1][1] = fmaf(h1, w4.y, acc[1][1]);
    acc[1][2] = fmaf(h1, w4.z, acc[1][2]); acc[1][3] = fmaf(h1, w4.w, acc[1][3]);
    acc[2][0] = fmaf(h2, w4.x, acc[2][0]); acc[2][1] = fmaf(h2, w4.y, acc[2][1]);
    acc[2][2] = fmaf(h2, w4.z, acc[2][2]); acc[2][3] = fmaf(h2, w4.w, acc[2][3]);
    acc[3][0] = fmaf(h3, w4.x, acc[3][0]); acc[3][1] = fmaf(h3, w4.y, acc[3][1]);
    acc[3][2] = fmaf(h3, w4.z, acc[3][2]); acc[3][3] = fmaf(h3, w4.w, acc[3][3]);
  }
#pragma unroll
  for (int j = 0; j < 4; ++j) {
    int row = r0 + rg * 4 + j;  // row = s*BB + b
    int bb = row & (BB - 1), st = row >> 5;
    size_t obase = ((size_t)bb * NSTEPS + st) * CC;
#pragma unroll
    for (int l = 0; l < 4; ++l) {
      int cc = c + l;
      if (cc < CC) out[obase + cc] = acc[j][l] + b_cls[cc];
    }
  }
}

extern "C" void kernel_launch(void* const* d_in, const int* in_sizes, int n_in,
                              void* d_out, int out_size, void* d_ws, size_t ws_size,
                              hipStream_t stream) {
  const float* x     = (const float*)d_in[0];
  const float* Wx    = (const float*)d_in[1];
  const float* Wh    = (const float*)d_in[2];
  const float* v     = (const float*)d_in[3];
  const float* W_ih  = (const float*)d_in[4];
  const float* W_hh  = (const float*)d_in[5];
  const float* b_ih  = (const float*)d_in[6];
  const float* b_hh  = (const float*)d_in[7];
  const float* W_cls = (const float*)d_in[8];
  const float* b_cls = (const float*)d_in[9];
  float* out = (float*)d_out;

  // workspace
  uintT* g_cnt    = (uintT*)d_ws;                           // 32 uints (pad 256)
  float* ctx_part = (float*)d_ws + 256;                     // 32*32*256
  float* den_part = ctx_part + (size_t)BB * NCHUNK * DD;    // 32*32
  float* hWh_buf  = den_part + BB * NCHUNK;                 // 32*128
  float* gi_buf   = hWh_buf + BB * AA;                      // 32*768
  float* gh_buf   = gi_buf + BB * 768;                      // 32*768
  float* hall     = gh_buf + BB * 768;                      // 22*32*256
  float* WclsT    = hall + (size_t)NSTEPS * BB * HH;        // 256*4480
  ushortT* WxT_bf = (ushortT*)(WclsT + (size_t)256 * CLS_LD);  // 128*256
  ushortT* x_bf   = WxT_bf + 128 * 256;                     // BT*256
  ushortT* xWT    = x_bf + (size_t)BB * TT * DD;            // B*A*T

  hipMemsetAsync(g_cnt, 0, 256 * sizeof(uintT), stream);
  trans_kernel<<<1096 + 32, 256, 0, stream>>>(Wx, W_cls, WclsT, WxT_bf);
  xw_mfma<<<(BB * TT) / 128, 256, 0, stream>>>(x, WxT_bf, x_bf, xWT);

  att_kernel<<<dim3(BB, NCHUNK), 256, 0, stream>>>(x_bf, xWT, nullptr, v, ctx_part, den_part);
  for (int s = 1; s <= NSTEPS; ++s) {
    gates_kernel<<<dim3(16, BB), 256, 0, stream>>>(ctx_part, den_part, hall, W_ih, W_hh,
                                                   b_ih, b_hh, Wh, gi_buf, gh_buf,
                                                   hall, hWh_buf, g_cnt, s);
    if (s < NSTEPS)
      att_kernel<<<dim3(BB, NCHUNK), 256, 0, stream>>>(x_bf, xWT, hWh_buf, v, ctx_part, den_part);
  }
  cls_kernel<<<dim3(35, 22), 256, 0, stream>>>(hall, WclsT, b_cls, out);
}

// Round 13
// 632.434 us; speedup vs baseline: 2.6585x; 2.6585x over previous
//
#include <hip/hip_runtime.h>

#define BB 32
#define TT 2048
#define DD 256
#define HH 256
#define AA 128
#define CC 4367
#define CLS_LD 4480   // 35*128, padded WclsT leading dim
#define NSTEPS 22
#define NCHUNK 32     // att t-chunks (64 t each)

typedef unsigned short ushortT;
typedef unsigned int uintT;
typedef unsigned long long u64T;
using frag8 = __attribute__((ext_vector_type(8))) short;
using f32x4 = __attribute__((ext_vector_type(4))) float;

__device__ __forceinline__ float tanh_fast(float u) {
  float e = __expf(2.0f * u);
  return 1.0f - 2.0f / (e + 1.0f);
}
__device__ __forceinline__ float sigmoid_fast(float u) {
  return 1.0f / (1.0f + __expf(-u));
}
__device__ __forceinline__ ushortT f2bf(float f) {
  unsigned int u = __float_as_uint(f);
  unsigned int r = (u + 0x7FFFu + ((u >> 16) & 1u)) >> 16;
  return (ushortT)r;
}
__device__ __forceinline__ float bf2f(ushortT v) {
  return __uint_as_float(((unsigned int)v) << 16);
}

// ---------- prep: WclsT fp32 [256][4480] and WxT_bf bf16 [128][256] ----------
__global__ __launch_bounds__(256) void trans_kernel(
    const float* __restrict__ Wx, const float* __restrict__ W_cls,
    float* __restrict__ WclsT, ushortT* __restrict__ WxT_bf) {
  int blk = blockIdx.x;
  __shared__ float tile[32][33];
  const int li = threadIdx.x >> 5, lj = threadIdx.x & 31;
  if (blk < 1096) {  // W_cls 4367x256 -> WclsT 256x4480
    int i0 = (blk >> 3) * 32, j0 = (blk & 7) * 32;
#pragma unroll
    for (int k = 0; k < 4; ++k) {
      int i = i0 + li + k * 8;
      if (i < CC) tile[li + k * 8][lj] = W_cls[(size_t)i * 256 + j0 + lj];
    }
    __syncthreads();
#pragma unroll
    for (int k = 0; k < 4; ++k) {
      int j = j0 + li + k * 8, i = i0 + lj;
      if (i < CC) WclsT[(size_t)j * CLS_LD + i] = tile[lj][li + k * 8];
    }
  } else {  // Wx 256x128 -> WxT_bf 128x256
    blk -= 1096;  // 0..31
    int i0 = (blk >> 2) * 32, j0 = (blk & 3) * 32;
#pragma unroll
    for (int k = 0; k < 4; ++k)
      tile[li + k * 8][lj] = Wx[(size_t)(i0 + li + k * 8) * 128 + j0 + lj];
    __syncthreads();
#pragma unroll
    for (int k = 0; k < 4; ++k) {
      int j = j0 + li + k * 8;
      WxT_bf[(size_t)j * 256 + i0 + lj] = f2bf(tile[lj][li + k * 8]);
    }
  }
}

// ---------- xW via MFMA bf16: block = 128 rows of [BT,256] x [256,128] ----------
// CHANGE vs r11: output layout is xW[b][t][a] (row = b*TT+t, natural D order,
// NO transpose-bounce) so att Phase A reads contiguous 64B per thread.
__global__ __launch_bounds__(256) void xw_mfma(
    const float* __restrict__ x, const ushortT* __restrict__ WxT_bf,
    ushortT* __restrict__ x_bf, ushortT* __restrict__ xW_ta) {
  __shared__ ushortT lds[2 * 128 * 72];  // sX | sW staging; reused as sT[128][136]
#define SX(r, c) lds[(r) * 72 + (c)]
#define SW(r, c) lds[128 * 72 + (r) * 72 + (c)]
#define ST(m, a) lds[(m) * 136 + (a)]
  const int tid = threadIdx.x;
  const int lane = tid & 63, w = tid >> 6;
  const int l15 = lane & 15, quad = lane >> 4;
  const int r0 = blockIdx.x * 128;
  const int row = tid >> 1, half = tid & 1;

  f32x4 acc[2][8];
#pragma unroll
  for (int mt = 0; mt < 2; ++mt)
#pragma unroll
    for (int nt = 0; nt < 8; ++nt) acc[mt][nt] = (f32x4){0.f, 0.f, 0.f, 0.f};

  for (int kk0 = 0; kk0 < 256; kk0 += 64) {
    // stage x (fp32 -> bf16) + write-through to x_bf
    {
      const float4* xp = (const float4*)(x + (size_t)(r0 + row) * DD + kk0 + half * 32);
      uint4 pk[4];
#pragma unroll
      for (int i = 0; i < 4; ++i) {
        float4 f0 = xp[2 * i], f1 = xp[2 * i + 1];
        pk[i].x = (uintT)f2bf(f0.x) | ((uintT)f2bf(f0.y) << 16);
        pk[i].y = (uintT)f2bf(f0.z) | ((uintT)f2bf(f0.w) << 16);
        pk[i].z = (uintT)f2bf(f1.x) | ((uintT)f2bf(f1.y) << 16);
        pk[i].w = (uintT)f2bf(f1.z) | ((uintT)f2bf(f1.w) << 16);
      }
      uint4* sxp = (uint4*)&SX(row, half * 32);
      uint4* gxp = (uint4*)(x_bf + (size_t)(r0 + row) * DD + kk0 + half * 32);
#pragma unroll
      for (int i = 0; i < 4; ++i) { sxp[i] = pk[i]; gxp[i] = pk[i]; }
    }
    // stage WxT_bf slice (n=row)
    {
      const uint4* wp = (const uint4*)(WxT_bf + (size_t)row * DD + kk0 + half * 32);
      uint4* swp = (uint4*)&SW(row, half * 32);
#pragma unroll
      for (int i = 0; i < 4; ++i) swp[i] = wp[i];
    }
    __syncthreads();
#pragma unroll
    for (int kk = 0; kk < 2; ++kk) {
      frag8 a0 = *(const frag8*)&SX(w * 32 + l15, kk * 32 + quad * 8);
      frag8 a1 = *(const frag8*)&SX(w * 32 + 16 + l15, kk * 32 + quad * 8);
#pragma unroll
      for (int nt = 0; nt < 8; ++nt) {
        frag8 bf = *(const frag8*)&SW(nt * 16 + l15, kk * 32 + quad * 8);
        acc[0][nt] = __builtin_amdgcn_mfma_f32_16x16x32_bf16(a0, bf, acc[0][nt], 0, 0, 0);
        acc[1][nt] = __builtin_amdgcn_mfma_f32_16x16x32_bf16(a1, bf, acc[1][nt], 0, 0, 0);
      }
    }
    __syncthreads();
  }
  // natural-order bounce: sT[m][a] = D[m][a], then write xW_ta[(r0+m)][a]
#pragma unroll
  for (int mt = 0; mt < 2; ++mt)
#pragma unroll
    for (int nt = 0; nt < 8; ++nt)
#pragma unroll
      for (int r = 0; r < 4; ++r) {
        int m = w * 32 + mt * 16 + quad * 4 + r;
        int a = nt * 16 + l15;
        ST(m, a) = f2bf(acc[mt][nt][r]);
      }
  __syncthreads();
  {
    const uint4* sp = (const uint4*)&ST(row, half * 64);
    uint4* gp = (uint4*)(xW_ta + (size_t)(r0 + row) * AA + half * 64);
#pragma unroll
    for (int i = 0; i < 8; ++i) gp[i] = sp[i];
  }
#undef SX
#undef SW
#undef ST
}

// ---------- gates: reduce ctx/den partials, then gi/gh dots (r11-exact) ----------
__global__ __launch_bounds__(256) void gates_kernel(
    const float* __restrict__ ctx_part, const float* __restrict__ den_part,
    const float* __restrict__ hall, const float* __restrict__ W_ih,
    const float* __restrict__ W_hh, const float* __restrict__ b_ih,
    const float* __restrict__ b_hh, float* __restrict__ gi_buf,
    float* __restrict__ gh_buf, int s) {
  const int slice = blockIdx.x, b = blockIdx.y, tid = threadIdx.x;
  __shared__ __align__(16) float sctx[DD];
  __shared__ float sden;
  if (tid < 32) {  // reduce den partials (one wave)
    float d = den_part[b * NCHUNK + tid];
#pragma unroll
    for (int off = 16; off > 0; off >>= 1) d += __shfl_down(d, off, 32);
    if (tid == 0) sden = d;
  }
  {  // reduce ctx partials: coalesced (256 lanes x 32 chunks)
    float acc = 0.f;
#pragma unroll
    for (int c = 0; c < NCHUNK; ++c)
      acc += ctx_part[((size_t)b * NCHUNK + c) * DD + tid];
    sctx[tid] = acc;
  }
  __syncthreads();
  const float invd = 1.0f / sden;
  const int kq = tid & 15, gsub = tid >> 4;  // gsub 0..15
  const float4* cp = (const float4*)sctx + kq * 4;
  const float4* hrow = (s >= 2) ? (const float4*)(hall + ((size_t)(s - 2) * BB + b) * HH) + kq * 4 : nullptr;
  float4 c4[4], h4[4];
#pragma unroll
  for (int j = 0; j < 4; ++j) {
    float4 cv = cp[j];
    c4[j].x = cv.x * invd; c4[j].y = cv.y * invd; c4[j].z = cv.z * invd; c4[j].w = cv.w * invd;
    if (hrow) h4[j] = hrow[j];
    else { h4[j].x = 0.f; h4[j].y = 0.f; h4[j].z = 0.f; h4[j].w = 0.f; }
  }
#pragma unroll
  for (int it = 0; it < 3; ++it) {
    const int g = slice * 48 + it * 16 + gsub;
    const float4* wi = (const float4*)(W_ih + (size_t)g * DD) + kq * 4;
    const float4* wh = (const float4*)(W_hh + (size_t)g * HH) + kq * 4;
    float gi = 0.f, gh = 0.f;
#pragma unroll
    for (int j = 0; j < 4; ++j) {
      float4 wv = wi[j];
      gi += c4[j].x * wv.x + c4[j].y * wv.y + c4[j].z * wv.z + c4[j].w * wv.w;
      wv = wh[j];
      gh += h4[j].x * wv.x + h4[j].y * wv.y + h4[j].z * wv.z + h4[j].w * wv.w;
    }
#pragma unroll
    for (int off = 8; off > 0; off >>= 1) {
      gi += __shfl_down(gi, off, 16);
      gh += __shfl_down(gh, off, 16);
    }
    if (kq == 0) {
      gi_buf[b * 768 + g] = gi + b_ih[g];
      gh_buf[b * 768 + g] = gh + b_hh[g];
    }
  }
}

// ---------- h-combine + hWh (r11-exact). grid (32 b, 4 a-slices), 256 thr ----------
__global__ __launch_bounds__(256) void hcomb_kernel(
    const float* __restrict__ gi_buf, const float* __restrict__ gh_buf,
    const float* __restrict__ Wh, float* __restrict__ hall,
    float* __restrict__ hWh_buf, int s) {
  const int b = blockIdx.x, as = blockIdx.y, i = threadIdx.x;
  __shared__ float sh[HH];
  __shared__ float part[8][32];
  {
    float gir = gi_buf[b * 768 + i], giz = gi_buf[b * 768 + 256 + i], gin = gi_buf[b * 768 + 512 + i];
    float ghr = gh_buf[b * 768 + i], ghz = gh_buf[b * 768 + 256 + i], ghn = gh_buf[b * 768 + 512 + i];
    float hp = (s >= 2) ? hall[((size_t)(s - 2) * BB + b) * HH + i] : 0.f;
    float r = sigmoid_fast(gir + ghr);
    float z = sigmoid_fast(giz + ghz);
    float n = tanh_fast(gin + r * ghn);
    float hv = (1.f - z) * n + z * hp;
    if (as == 0) hall[((size_t)(s - 1) * BB + b) * HH + i] = hv;
    sh[i] = hv;
  }
  __syncthreads();
  {
    const int a = i & 31, kq = i >> 5;
    const int ga = as * 32 + a;
    float acc = 0.f;
#pragma unroll
    for (int k = kq * 32; k < kq * 32 + 32; ++k)
      acc = fmaf(sh[k], Wh[k * AA + ga], acc);
    part[kq][a] = acc;
  }
  __syncthreads();
  if (i < 32) {
    float sum = part[0][i] + part[1][i] + part[2][i] + part[3][i]
              + part[4][i] + part[5][i] + part[6][i] + part[7][i];
    hWh_buf[b * AA + as * 32 + i] = sum;
  }
}

// ---------- per-step attention. grid (32 b, 32 chunks), 256 thr ----------
// CHANGE vs r11: Phase A consumes xW[b][t][a] — thread (tl = t-local, aseg)
// reads 64 CONTIGUOUS bytes (4x uint4) instead of 16 loads at 4KB stride;
// per-t score reduce is 2 shfl_xor (width 4) — sh_part LDS buffer and one
// barrier removed. x prefetch still issues after the first barrier (r11 win).
__global__ __launch_bounds__(256, 4) void att_kernel(
    const ushortT* __restrict__ x_bf, const ushortT* __restrict__ xW_ta,
    const float* __restrict__ hWh_buf, const float* __restrict__ v,
    float* __restrict__ ctx_part, float* __restrict__ den_part) {
  const int tid = threadIdx.x;
  const int b = blockIdx.x;
  const int chunk = blockIdx.y;  // 0..31, 64 t's each
  const int t0 = chunk * 64;
  __shared__ float sh_hWh[AA], sh_v[AA];
  __shared__ float sh_w[64];
  __shared__ __align__(16) float sh_ctx[4 * DD];
  if (tid < AA) {
    sh_hWh[tid] = hWh_buf ? hWh_buf[b * AA + tid] : 0.f;
    sh_v[tid] = v[tid];
  }
  __syncthreads();  // waits only the 128-lane LDS stores above
  // x prefetch issues HERE: overlaps with all of Phase A
  const int j4 = tid >> 6, dq = tid & 63;
  u64T xr[16];
  {
    const u64T* xb4 = (const u64T*)x_bf;
#pragma unroll
    for (int j = 0; j < 16; ++j)
      xr[j] = __builtin_nontemporal_load(
          &xb4[(((size_t)(b * TT + t0 + j * 4 + j4)) * DD >> 2) + dq]);
  }
  // Phase A: scores. thread = (tl = tid>>2 in [0,64), aseg = tid&3 owns 32 a's)
  {
    const int tl = tid >> 2, aseg = tid & 3;
    const uint4* xw16 = (const uint4*)(xW_ta + (size_t)(b * TT + t0 + tl) * AA + aseg * 32);
    float e = 0.f;
#pragma unroll
    for (int i = 0; i < 4; ++i) {
      uint4 u = xw16[i];
      const int ab = aseg * 32 + i * 8;
      e = fmaf(tanh_fast(bf2f((ushortT)(u.x & 0xFFFFu)) + sh_hWh[ab + 0]), sh_v[ab + 0], e);
      e = fmaf(tanh_fast(bf2f((ushortT)(u.x >> 16)) + sh_hWh[ab + 1]), sh_v[ab + 1], e);
      e = fmaf(tanh_fast(bf2f((ushortT)(u.y & 0xFFFFu)) + sh_hWh[ab + 2]), sh_v[ab + 2], e);
      e = fmaf(tanh_fast(bf2f((ushortT)(u.y >> 16)) + sh_hWh[ab + 3]), sh_v[ab + 3], e);
      e = fmaf(tanh_fast(bf2f((ushortT)(u.z & 0xFFFFu)) + sh_hWh[ab + 4]), sh_v[ab + 4], e);
      e = fmaf(tanh_fast(bf2f((ushortT)(u.z >> 16)) + sh_hWh[ab + 5]), sh_v[ab + 5], e);
      e = fmaf(tanh_fast(bf2f((ushortT)(u.w & 0xFFFFu)) + sh_hWh[ab + 6]), sh_v[ab + 6], e);
      e = fmaf(tanh_fast(bf2f((ushortT)(u.w >> 16)) + sh_hWh[ab + 7]), sh_v[ab + 7], e);
    }
    e += __shfl_xor(e, 1, 4);
    e += __shfl_xor(e, 2, 4);
    if (aseg == 0) sh_w[tl] = __expf(e);  // |e| <= ||v||_1 ~ 5: safe, no max-pass
  }
  __syncthreads();
  // Phase B: ctx partials from prefetched regs (unpack u64 -> 4 bf16)
  {
    float4 acc = {0.f, 0.f, 0.f, 0.f};
#pragma unroll
    for (int j = 0; j < 16; ++j) {
      float w = sh_w[j * 4 + j4];
      u64T u = xr[j];
      acc.x = fmaf(w, bf2f((ushortT)(u       & 0xFFFFu)), acc.x);
      acc.y = fmaf(w, bf2f((ushortT)((u >> 16) & 0xFFFFu)), acc.y);
      acc.z = fmaf(w, bf2f((ushortT)((u >> 32) & 0xFFFFu)), acc.z);
      acc.w = fmaf(w, bf2f((ushortT)((u >> 48) & 0xFFFFu)), acc.w);
    }
    ((float4*)sh_ctx)[j4 * 64 + dq] = acc;
  }
  __syncthreads();
  {
    float sum = sh_ctx[tid] + sh_ctx[DD + tid] + sh_ctx[2 * DD + tid] + sh_ctx[3 * DD + tid];
    ctx_part[((size_t)b * NCHUNK + chunk) * DD + tid] = sum;  // plain coalesced store
  }
  if (tid < 64) {
    float ds = sh_w[tid];
#pragma unroll
    for (int off = 32; off > 0; off >>= 1) ds += __shfl_down(ds, off, 64);
    if (tid == 0) den_part[b * NCHUNK + chunk] = ds;
  }
}

// ---------- final: out[b,s,c] = hall[s,b,:] @ W_cls^T + b_cls ----------
// r1-EXACT (measured 45.0 us — best of 5 variants; cls frozen).
__global__ __launch_bounds__(256) void cls_kernel(
    const float* __restrict__ hall, const float* __restrict__ WclsT,
    const float* __restrict__ b_cls, float* __restrict__ out) {
  const int tid = threadIdx.x;
  const int c0 = blockIdx.x * 128;
  const int r0 = blockIdx.y * 32;
  const int cq = tid & 31, rg = tid >> 5;
  const int c = c0 + cq * 4;
  __shared__ __align__(16) float shh[32 * HH];
  {
    const float4* hsrc = (const float4*)(hall + (size_t)r0 * HH);
    float4* hdst = (float4*)shh;
#pragma unroll
    for (int i = 0; i < 8; ++i) hdst[tid + 256 * i] = hsrc[tid + 256 * i];
  }
  __syncthreads();
  float acc[4][4];
#pragma unroll
  for (int j = 0; j < 4; ++j)
#pragma unroll
    for (int l = 0; l < 4; ++l) acc[j][l] = 0.f;
#pragma unroll 4
  for (int k = 0; k < HH; ++k) {
    float4 w4 = *(const float4*)(WclsT + (size_t)k * CLS_LD + c);
    float h0 = shh[(rg * 4 + 0) * HH + k];
    float h1 = shh[(rg * 4 + 1) * HH + k];
    float h2 = shh[(rg * 4 + 2) * HH + k];
    float h3 = shh[(rg * 4 + 3) * HH + k];
    acc[0][0] = fmaf(h0, w4.x, acc[0][0]); acc[0][1] = fmaf(h0, w4.y, acc[0][1]);
    acc[0][2] = fmaf(h0, w4.z, acc[0][2]); acc[0][3] = fmaf(h0, w4.w, acc[0][3]);
    acc[1][0] = fmaf(h1, w4.x, acc[1][0]); acc[1][1] = fmaf(h1, w4.y, acc[1][1]);
    acc[1][2] = fmaf(h1, w4.z, acc[1][2]); acc[1][3] = fmaf(h1, w4.w, acc[1][3]);
    acc[2][0] = fmaf(h2, w4.x, acc[2][0]); acc[2][1] = fmaf(h2, w4.y, acc[2][1]);
    acc[2][2] = fmaf(h2, w4.z, acc[2][2]); acc[2][3] = fmaf(h2, w4.w, acc[2][3]);
    acc[3][0] = fmaf(h3, w4.x, acc[3][0]); acc[3][1] = fmaf(h3, w4.y, acc[3][1]);
    acc[3][2] = fmaf(h3, w4.z, acc[3][2]); acc[3][3] = fmaf(h3, w4.w, acc[3][3]);
  }
#pragma unroll
  for (int j = 0; j < 4; ++j) {
    int row = r0 + rg * 4 + j;  // row = s*BB + b
    int bb = row & (BB - 1), st = row >> 5;
    size_t obase = ((size_t)bb * NSTEPS + st) * CC;
#pragma unroll
    for (int l = 0; l < 4; ++l) {
      int cc = c + l;
      if (cc < CC) out[obase + cc] = acc[j][l] + b_cls[cc];
    }
  }
}

extern "C" void kernel_launch(void* const* d_in, const int* in_sizes, int n_in,
                              void* d_out, int out_size, void* d_ws, size_t ws_size,
                              hipStream_t stream) {
  const float* x     = (const float*)d_in[0];
  const float* Wx    = (const float*)d_in[1];
  const float* Wh    = (const float*)d_in[2];
  const float* v     = (const float*)d_in[3];
  const float* W_ih  = (const float*)d_in[4];
  const float* W_hh  = (const float*)d_in[5];
  const float* b_ih  = (const float*)d_in[6];
  const float* b_hh  = (const float*)d_in[7];
  const float* W_cls = (const float*)d_in[8];
  const float* b_cls = (const float*)d_in[9];
  float* out = (float*)d_out;

  // workspace
  float* ctx_part = (float*)d_ws;                           // 32*32*256
  float* den_part = ctx_part + (size_t)BB * NCHUNK * DD;    // 32*32
  float* hWh_buf  = den_part + BB * NCHUNK;                 // 32*128
  float* gi_buf   = hWh_buf + BB * AA;                      // 32*768
  float* gh_buf   = gi_buf + BB * 768;                      // 32*768
  float* hall     = gh_buf + BB * 768;                      // 22*32*256
  float* WclsT    = hall + (size_t)NSTEPS * BB * HH;        // 256*4480
  ushortT* WxT_bf = (ushortT*)(WclsT + (size_t)256 * CLS_LD);  // 128*256
  ushortT* x_bf   = WxT_bf + 128 * 256;                     // BT*256
  ushortT* xW_ta  = x_bf + (size_t)BB * TT * DD;            // B*T*A

  trans_kernel<<<1096 + 32, 256, 0, stream>>>(Wx, W_cls, WclsT, WxT_bf);
  xw_mfma<<<(BB * TT) / 128, 256, 0, stream>>>(x, WxT_bf, x_bf, xW_ta);

  att_kernel<<<dim3(BB, NCHUNK), 256, 0, stream>>>(x_bf, xW_ta, nullptr, v, ctx_part, den_part);
  for (int s = 1; s < NSTEPS; ++s) {
    gates_kernel<<<dim3(16, BB), 256, 0, stream>>>(ctx_part, den_part, hall, W_ih, W_hh,
                                                   b_ih, b_hh, gi_buf, gh_buf, s);
    hcomb_kernel<<<dim3(BB, 4), 256, 0, stream>>>(gi_buf, gh_buf, Wh, hall, hWh_buf, s);
    att_kernel<<<dim3(BB, NCHUNK), 256, 0, stream>>>(x_bf, xW_ta, hWh_buf, v, ctx_part, den_part);
  }
  gates_kernel<<<dim3(16, BB), 256, 0, stream>>>(ctx_part, den_part, hall, W_ih, W_hh,
                                                 b_ih, b_hh, gi_buf, gh_buf, NSTEPS);
  hcomb_kernel<<<dim3(BB, 4), 256, 0, stream>>>(gi_buf, gh_buf, Wh, hall, hWh_buf, NSTEPS);
  cls_kernel<<<dim3(35, 22), 256, 0, stream>>>(hall, WclsT, b_cls, out);
}

// Round 14
// 598.930 us; speedup vs baseline: 2.8072x; 1.0559x over previous
//
#include <hip/hip_runtime.h>

#define BB 32
#define TT 2048
#define DD 256
#define HH 256
#define AA 128
#define CC 4367
#define CLS_LD 4480   // 35*128, padded WclsT leading dim
#define NSTEPS 22
#define NCHUNK 32     // att t-chunks (64 t each)

typedef unsigned short ushortT;
typedef unsigned int uintT;
typedef unsigned long long u64T;
using frag8 = __attribute__((ext_vector_type(8))) short;
using f32x4 = __attribute__((ext_vector_type(4))) float;

__device__ __forceinline__ float tanh_fast(float u) {
  float e = __expf(2.0f * u);
  return 1.0f - 2.0f / (e + 1.0f);
}
__device__ __forceinline__ float sigmoid_fast(float u) {
  return 1.0f / (1.0f + __expf(-u));
}
__device__ __forceinline__ ushortT f2bf(float f) {
  unsigned int u = __float_as_uint(f);
  unsigned int r = (u + 0x7FFFu + ((u >> 16) & 1u)) >> 16;
  return (ushortT)r;
}
__device__ __forceinline__ float bf2f(ushortT v) {
  return __uint_as_float(((unsigned int)v) << 16);
}

// ---------- prep: WclsT fp32 [256][4480] and WxT_bf bf16 [128][256] ----------
__global__ __launch_bounds__(256) void trans_kernel(
    const float* __restrict__ Wx, const float* __restrict__ W_cls,
    float* __restrict__ WclsT, ushortT* __restrict__ WxT_bf) {
  int blk = blockIdx.x;
  __shared__ float tile[32][33];
  const int li = threadIdx.x >> 5, lj = threadIdx.x & 31;
  if (blk < 1096) {  // W_cls 4367x256 -> WclsT 256x4480
    int i0 = (blk >> 3) * 32, j0 = (blk & 7) * 32;
#pragma unroll
    for (int k = 0; k < 4; ++k) {
      int i = i0 + li + k * 8;
      if (i < CC) tile[li + k * 8][lj] = W_cls[(size_t)i * 256 + j0 + lj];
    }
    __syncthreads();
#pragma unroll
    for (int k = 0; k < 4; ++k) {
      int j = j0 + li + k * 8, i = i0 + lj;
      if (i < CC) WclsT[(size_t)j * CLS_LD + i] = tile[lj][li + k * 8];
    }
  } else {  // Wx 256x128 -> WxT_bf 128x256
    blk -= 1096;  // 0..31
    int i0 = (blk >> 2) * 32, j0 = (blk & 3) * 32;
#pragma unroll
    for (int k = 0; k < 4; ++k)
      tile[li + k * 8][lj] = Wx[(size_t)(i0 + li + k * 8) * 128 + j0 + lj];
    __syncthreads();
#pragma unroll
    for (int k = 0; k < 4; ++k) {
      int j = j0 + li + k * 8;
      WxT_bf[(size_t)j * 256 + i0 + lj] = f2bf(tile[lj][li + k * 8]);
    }
  }
}

// ---------- xW via MFMA bf16: block = 128 rows of [BT,256] x [256,128] ----------
// Output layout xW[b][t][a] (r13): natural D order, no transpose-bounce.
__global__ __launch_bounds__(256) void xw_mfma(
    const float* __restrict__ x, const ushortT* __restrict__ WxT_bf,
    ushortT* __restrict__ x_bf, ushortT* __restrict__ xW_ta) {
  __shared__ ushortT lds[2 * 128 * 72];  // sX | sW staging; reused as sT[128][136]
#define SX(r, c) lds[(r) * 72 + (c)]
#define SW(r, c) lds[128 * 72 + (r) * 72 + (c)]
#define ST(m, a) lds[(m) * 136 + (a)]
  const int tid = threadIdx.x;
  const int lane = tid & 63, w = tid >> 6;
  const int l15 = lane & 15, quad = lane >> 4;
  const int r0 = blockIdx.x * 128;
  const int row = tid >> 1, half = tid & 1;

  f32x4 acc[2][8];
#pragma unroll
  for (int mt = 0; mt < 2; ++mt)
#pragma unroll
    for (int nt = 0; nt < 8; ++nt) acc[mt][nt] = (f32x4){0.f, 0.f, 0.f, 0.f};

  for (int kk0 = 0; kk0 < 256; kk0 += 64) {
    // stage x (fp32 -> bf16) + write-through to x_bf
    {
      const float4* xp = (const float4*)(x + (size_t)(r0 + row) * DD + kk0 + half * 32);
      uint4 pk[4];
#pragma unroll
      for (int i = 0; i < 4; ++i) {
        float4 f0 = xp[2 * i], f1 = xp[2 * i + 1];
        pk[i].x = (uintT)f2bf(f0.x) | ((uintT)f2bf(f0.y) << 16);
        pk[i].y = (uintT)f2bf(f0.z) | ((uintT)f2bf(f0.w) << 16);
        pk[i].z = (uintT)f2bf(f1.x) | ((uintT)f2bf(f1.y) << 16);
        pk[i].w = (uintT)f2bf(f1.z) | ((uintT)f2bf(f1.w) << 16);
      }
      uint4* sxp = (uint4*)&SX(row, half * 32);
      uint4* gxp = (uint4*)(x_bf + (size_t)(r0 + row) * DD + kk0 + half * 32);
#pragma unroll
      for (int i = 0; i < 4; ++i) { sxp[i] = pk[i]; gxp[i] = pk[i]; }
    }
    // stage WxT_bf slice (n=row)
    {
      const uint4* wp = (const uint4*)(WxT_bf + (size_t)row * DD + kk0 + half * 32);
      uint4* swp = (uint4*)&SW(row, half * 32);
#pragma unroll
      for (int i = 0; i < 4; ++i) swp[i] = wp[i];
    }
    __syncthreads();
#pragma unroll
    for (int kk = 0; kk < 2; ++kk) {
      frag8 a0 = *(const frag8*)&SX(w * 32 + l15, kk * 32 + quad * 8);
      frag8 a1 = *(const frag8*)&SX(w * 32 + 16 + l15, kk * 32 + quad * 8);
#pragma unroll
      for (int nt = 0; nt < 8; ++nt) {
        frag8 bf = *(const frag8*)&SW(nt * 16 + l15, kk * 32 + quad * 8);
        acc[0][nt] = __builtin_amdgcn_mfma_f32_16x16x32_bf16(a0, bf, acc[0][nt], 0, 0, 0);
        acc[1][nt] = __builtin_amdgcn_mfma_f32_16x16x32_bf16(a1, bf, acc[1][nt], 0, 0, 0);
      }
    }
    __syncthreads();
  }
  // natural-order bounce: sT[m][a] = D[m][a], then write xW_ta[(r0+m)][a]
#pragma unroll
  for (int mt = 0; mt < 2; ++mt)
#pragma unroll
    for (int nt = 0; nt < 8; ++nt)
#pragma unroll
      for (int r = 0; r < 4; ++r) {
        int m = w * 32 + mt * 16 + quad * 4 + r;
        int a = nt * 16 + l15;
        ST(m, a) = f2bf(acc[mt][nt][r]);
      }
  __syncthreads();
  {
    const uint4* sp = (const uint4*)&ST(row, half * 64);
    uint4* gp = (uint4*)(xW_ta + (size_t)(r0 + row) * AA + half * 64);
#pragma unroll
    for (int i = 0; i < 8; ++i) gp[i] = sp[i];
  }
#undef SX
#undef SW
#undef ST
}

// ---------- gates v2: all-3-gates-per-slice + in-block h-combine + partial hWh ----------
// grid (16 slices, 32 b), 256 thr. Slice sl owns hidden elements
// i = sl*16 .. sl*16+15 and computes rows {it*256 + sl*16 + g} for it=0..2 —
// all three gates for its elements. The 16-lane team for element g accumulates
// (gi,gh) across the it-loop IN REGISTERS, so h-combine is local (no gi/gh
// global buffers, no hcomb kernel, no fences). Tail: write hall slice +
// partial hWh over this block's 16 k's (8 KB of Wh; total Wh traffic
// unchanged). att reduces the 16 partials. Kernel boundaries = ordering.
__global__ __launch_bounds__(256) void gates_kernel(
    const float* __restrict__ ctx_part, const float* __restrict__ den_part,
    const float* __restrict__ hall_c, const float* __restrict__ W_ih,
    const float* __restrict__ W_hh, const float* __restrict__ b_ih,
    const float* __restrict__ b_hh, const float* __restrict__ Wh,
    float* __restrict__ hall, float* __restrict__ hWh_part, int s) {
  const int sl = blockIdx.x, b = blockIdx.y, tid = threadIdx.x;
  __shared__ __align__(16) float sctx[DD];
  __shared__ float sden;
  __shared__ float sh16[16];
  if (tid < 32) {  // reduce den partials (one wave)
    float d = den_part[b * NCHUNK + tid];
#pragma unroll
    for (int off = 16; off > 0; off >>= 1) d += __shfl_down(d, off, 32);
    if (tid == 0) sden = d;
  }
  {  // reduce ctx partials: coalesced (256 lanes x 32 chunks)
    float acc = 0.f;
#pragma unroll
    for (int c = 0; c < NCHUNK; ++c)
      acc += ctx_part[((size_t)b * NCHUNK + c) * DD + tid];
    sctx[tid] = acc;
  }
  __syncthreads();
  const float invd = 1.0f / sden;
  const int kq = tid & 15, gsub = tid >> 4;  // gsub 0..15 = element within slice
  const float4* cp = (const float4*)sctx + kq * 4;
  const float4* hrow = (s >= 2) ? (const float4*)(hall_c + ((size_t)(s - 2) * BB + b) * HH) + kq * 4 : nullptr;
  float4 c4[4], h4[4];
#pragma unroll
  for (int j = 0; j < 4; ++j) {
    float4 cv = cp[j];
    c4[j].x = cv.x * invd; c4[j].y = cv.y * invd; c4[j].z = cv.z * invd; c4[j].w = cv.w * invd;
    if (hrow) h4[j] = hrow[j];
    else { h4[j].x = 0.f; h4[j].y = 0.f; h4[j].z = 0.f; h4[j].w = 0.f; }
  }
  float gi_g[3], gh_g[3];
#pragma unroll
  for (int it = 0; it < 3; ++it) {
    const int g = it * 256 + sl * 16 + gsub;
    const float4* wi = (const float4*)(W_ih + (size_t)g * DD) + kq * 4;
    const float4* wh = (const float4*)(W_hh + (size_t)g * HH) + kq * 4;
    float gi = 0.f, gh = 0.f;
#pragma unroll
    for (int j = 0; j < 4; ++j) {
      float4 wv = wi[j];
      gi += c4[j].x * wv.x + c4[j].y * wv.y + c4[j].z * wv.z + c4[j].w * wv.w;
      wv = wh[j];
      gh += h4[j].x * wv.x + h4[j].y * wv.y + h4[j].z * wv.z + h4[j].w * wv.w;
    }
#pragma unroll
    for (int off = 8; off > 0; off >>= 1) {
      gi += __shfl_down(gi, off, 16);
      gh += __shfl_down(gh, off, 16);
    }
    gi_g[it] = gi + b_ih[g];  // valid on kq==0 lane (the only consumer)
    gh_g[it] = gh + b_hh[g];
  }
  if (kq == 0) {  // h-combine for element i = sl*16 + gsub, fully in registers
    const int i = sl * 16 + gsub;
    float hp = (s >= 2) ? hall_c[((size_t)(s - 2) * BB + b) * HH + i] : 0.f;
    float r = sigmoid_fast(gi_g[0] + gh_g[0]);
    float z = sigmoid_fast(gi_g[1] + gh_g[1]);
    float n = tanh_fast(gi_g[2] + r * gh_g[2]);
    float hv = (1.f - z) * n + z * hp;
    hall[((size_t)(s - 1) * BB + b) * HH + i] = hv;
    sh16[gsub] = hv;
  }
  __syncthreads();
  if (tid < AA) {  // partial hWh over this block's 16 k's (coalesced Wh rows)
    float acc = 0.f;
#pragma unroll
    for (int k = 0; k < 16; ++k)
      acc = fmaf(sh16[k], Wh[(size_t)(sl * 16 + k) * AA + tid], acc);
    hWh_part[((size_t)b * 16 + sl) * AA + tid] = acc;
  }
}

// ---------- per-step attention. grid (32 b, 32 chunks), 256 thr ----------
// Prologue change vs r13: sh_hWh = sum of 16 per-slice partials (8 KB, L2-hot).
__global__ __launch_bounds__(256, 4) void att_kernel(
    const ushortT* __restrict__ x_bf, const ushortT* __restrict__ xW_ta,
    const float* __restrict__ hWh_part, const float* __restrict__ v,
    float* __restrict__ ctx_part, float* __restrict__ den_part) {
  const int tid = threadIdx.x;
  const int b = blockIdx.x;
  const int chunk = blockIdx.y;  // 0..31, 64 t's each
  const int t0 = chunk * 64;
  __shared__ float sh_hWh[AA], sh_v[AA];
  __shared__ float sh_w[64];
  __shared__ __align__(16) float sh_ctx[4 * DD];
  if (tid < AA) {
    float hw = 0.f;
    if (hWh_part) {
#pragma unroll
      for (int sl = 0; sl < 16; ++sl)
        hw += hWh_part[((size_t)b * 16 + sl) * AA + tid];
    }
    sh_hWh[tid] = hw;
    sh_v[tid] = v[tid];
  }
  __syncthreads();  // waits only the 128-lane LDS stores above
  // x prefetch issues HERE: overlaps with all of Phase A (r11 win)
  const int j4 = tid >> 6, dq = tid & 63;
  u64T xr[16];
  {
    const u64T* xb4 = (const u64T*)x_bf;
#pragma unroll
    for (int j = 0; j < 16; ++j)
      xr[j] = __builtin_nontemporal_load(
          &xb4[(((size_t)(b * TT + t0 + j * 4 + j4)) * DD >> 2) + dq]);
  }
  // Phase A: scores. thread = (tl = tid>>2 in [0,64), aseg = tid&3 owns 32 a's)
  {
    const int tl = tid >> 2, aseg = tid & 3;
    const uint4* xw16 = (const uint4*)(xW_ta + (size_t)(b * TT + t0 + tl) * AA + aseg * 32);
    float e = 0.f;
#pragma unroll
    for (int i = 0; i < 4; ++i) {
      uint4 u = xw16[i];
      const int ab = aseg * 32 + i * 8;
      e = fmaf(tanh_fast(bf2f((ushortT)(u.x & 0xFFFFu)) + sh_hWh[ab + 0]), sh_v[ab + 0], e);
      e = fmaf(tanh_fast(bf2f((ushortT)(u.x >> 16)) + sh_hWh[ab + 1]), sh_v[ab + 1], e);
      e = fmaf(tanh_fast(bf2f((ushortT)(u.y & 0xFFFFu)) + sh_hWh[ab + 2]), sh_v[ab + 2], e);
      e = fmaf(tanh_fast(bf2f((ushortT)(u.y >> 16)) + sh_hWh[ab + 3]), sh_v[ab + 3], e);
      e = fmaf(tanh_fast(bf2f((ushortT)(u.z & 0xFFFFu)) + sh_hWh[ab + 4]), sh_v[ab + 4], e);
      e = fmaf(tanh_fast(bf2f((ushortT)(u.z >> 16)) + sh_hWh[ab + 5]), sh_v[ab + 5], e);
      e = fmaf(tanh_fast(bf2f((ushortT)(u.w & 0xFFFFu)) + sh_hWh[ab + 6]), sh_v[ab + 6], e);
      e = fmaf(tanh_fast(bf2f((ushortT)(u.w >> 16)) + sh_hWh[ab + 7]), sh_v[ab + 7], e);
    }
    e += __shfl_xor(e, 1, 4);
    e += __shfl_xor(e, 2, 4);
    if (aseg == 0) sh_w[tl] = __expf(e);  // |e| <= ||v||_1 ~ 5: safe, no max-pass
  }
  __syncthreads();
  // Phase B: ctx partials from prefetched regs (unpack u64 -> 4 bf16)
  {
    float4 acc = {0.f, 0.f, 0.f, 0.f};
#pragma unroll
    for (int j = 0; j < 16; ++j) {
      float w = sh_w[j * 4 + j4];
      u64T u = xr[j];
      acc.x = fmaf(w, bf2f((ushortT)(u       & 0xFFFFu)), acc.x);
      acc.y = fmaf(w, bf2f((ushortT)((u >> 16) & 0xFFFFu)), acc.y);
      acc.z = fmaf(w, bf2f((ushortT)((u >> 32) & 0xFFFFu)), acc.z);
      acc.w = fmaf(w, bf2f((ushortT)((u >> 48) & 0xFFFFu)), acc.w);
    }
    ((float4*)sh_ctx)[j4 * 64 + dq] = acc;
  }
  __syncthreads();
  {
    float sum = sh_ctx[tid] + sh_ctx[DD + tid] + sh_ctx[2 * DD + tid] + sh_ctx[3 * DD + tid];
    ctx_part[((size_t)b * NCHUNK + chunk) * DD + tid] = sum;  // plain coalesced store
  }
  if (tid < 64) {
    float ds = sh_w[tid];
#pragma unroll
    for (int off = 32; off > 0; off >>= 1) ds += __shfl_down(ds, off, 64);
    if (tid == 0) den_part[b * NCHUNK + chunk] = ds;
  }
}

// ---------- final: out[b,s,c] = hall[s,b,:] @ W_cls^T + b_cls ----------
// r1-EXACT (measured 45.0 us — best of 5 variants; cls frozen).
__global__ __launch_bounds__(256) void cls_kernel(
    const float* __restrict__ hall, const float* __restrict__ WclsT,
    const float* __restrict__ b_cls, float* __restrict__ out) {
  const int tid = threadIdx.x;
  const int c0 = blockIdx.x * 128;
  const int r0 = blockIdx.y * 32;
  const int cq = tid & 31, rg = tid >> 5;
  const int c = c0 + cq * 4;
  __shared__ __align__(16) float shh[32 * HH];
  {
    const float4* hsrc = (const float4*)(hall + (size_t)r0 * HH);
    float4* hdst = (float4*)shh;
#pragma unroll
    for (int i = 0; i < 8; ++i) hdst[tid + 256 * i] = hsrc[tid + 256 * i];
  }
  __syncthreads();
  float acc[4][4];
#pragma unroll
  for (int j = 0; j < 4; ++j)
#pragma unroll
    for (int l = 0; l < 4; ++l) acc[j][l] = 0.f;
#pragma unroll 4
  for (int k = 0; k < HH; ++k) {
    float4 w4 = *(const float4*)(WclsT + (size_t)k * CLS_LD + c);
    float h0 = shh[(rg * 4 + 0) * HH + k];
    float h1 = shh[(rg * 4 + 1) * HH + k];
    float h2 = shh[(rg * 4 + 2) * HH + k];
    float h3 = shh[(rg * 4 + 3) * HH + k];
    acc[0][0] = fmaf(h0, w4.x, acc[0][0]); acc[0][1] = fmaf(h0, w4.y, acc[0][1]);
    acc[0][2] = fmaf(h0, w4.z, acc[0][2]); acc[0][3] = fmaf(h0, w4.w, acc[0][3]);
    acc[1][0] = fmaf(h1, w4.x, acc[1][0]); acc[1][1] = fmaf(h1, w4.y, acc[1][1]);
    acc[1][2] = fmaf(h1, w4.z, acc[1][2]); acc[1][3] = fmaf(h1, w4.w, acc[1][3]);
    acc[2][0] = fmaf(h2, w4.x, acc[2][0]); acc[2][1] = fmaf(h2, w4.y, acc[2][1]);
    acc[2][2] = fmaf(h2, w4.z, acc[2][2]); acc[2][3] = fmaf(h2, w4.w, acc[2][3]);
    acc[3][0] = fmaf(h3, w4.x, acc[3][0]); acc[3][1] = fmaf(h3, w4.y, acc[3][1]);
    acc[3][2] = fmaf(h3, w4.z, acc[3][2]); acc[3][3] = fmaf(h3, w4.w, acc[3][3]);
  }
#pragma unroll
  for (int j = 0; j < 4; ++j) {
    int row = r0 + rg * 4 + j;  // row = s*BB + b
    int bb = row & (BB - 1), st = row >> 5;
    size_t obase = ((size_t)bb * NSTEPS + st) * CC;
#pragma unroll
    for (int l = 0; l < 4; ++l) {
      int cc = c + l;
      if (cc < CC) out[obase + cc] = acc[j][l] + b_cls[cc];
    }
  }
}

extern "C" void kernel_launch(void* const* d_in, const int* in_sizes, int n_in,
                              void* d_out, int out_size, void* d_ws, size_t ws_size,
                              hipStream_t stream) {
  const float* x     = (const float*)d_in[0];
  const float* Wx    = (const float*)d_in[1];
  const float* Wh    = (const float*)d_in[2];
  const float* v     = (const float*)d_in[3];
  const float* W_ih  = (const float*)d_in[4];
  const float* W_hh  = (const float*)d_in[5];
  const float* b_ih  = (const float*)d_in[6];
  const float* b_hh  = (const float*)d_in[7];
  const float* W_cls = (const float*)d_in[8];
  const float* b_cls = (const float*)d_in[9];
  float* out = (float*)d_out;

  // workspace
  float* ctx_part = (float*)d_ws;                           // 32*32*256
  float* den_part = ctx_part + (size_t)BB * NCHUNK * DD;    // 32*32
  float* hWh_part = den_part + BB * NCHUNK;                 // 32*16*128
  float* hall     = hWh_part + (size_t)BB * 16 * AA;        // 22*32*256
  float* WclsT    = hall + (size_t)NSTEPS * BB * HH;        // 256*4480
  ushortT* WxT_bf = (ushortT*)(WclsT + (size_t)256 * CLS_LD);  // 128*256
  ushortT* x_bf   = WxT_bf + 128 * 256;                     // BT*256
  ushortT* xW_ta  = x_bf + (size_t)BB * TT * DD;            // B*T*A

  trans_kernel<<<1096 + 32, 256, 0, stream>>>(Wx, W_cls, WclsT, WxT_bf);
  xw_mfma<<<(BB * TT) / 128, 256, 0, stream>>>(x, WxT_bf, x_bf, xW_ta);

  att_kernel<<<dim3(BB, NCHUNK), 256, 0, stream>>>(x_bf, xW_ta, nullptr, v, ctx_part, den_part);
  for (int s = 1; s <= NSTEPS; ++s) {
    gates_kernel<<<dim3(16, BB), 256, 0, stream>>>(ctx_part, den_part, hall, W_ih, W_hh,
                                                   b_ih, b_hh, Wh, hall, hWh_part, s);
    if (s < NSTEPS)
      att_kernel<<<dim3(BB, NCHUNK), 256, 0, stream>>>(x_bf, xW_ta, hWh_part, v, ctx_part, den_part);
  }
  cls_kernel<<<dim3(35, 22), 256, 0, stream>>>(hall, WclsT, b_cls, out);
}

// Round 15
// 595.985 us; speedup vs baseline: 2.8211x; 1.0049x over previous
//
#include <hip/hip_runtime.h>

#define BB 32
#define TT 2048
#define DD 256
#define HH 256
#define AA 128
#define CC 4367
#define CLS_LD 4480   // 35*128, padded WclsT leading dim
#define NSTEPS 22
#define NCHUNK 32     // att t-chunks (64 t each)

typedef unsigned short ushortT;
typedef unsigned int uintT;
typedef unsigned long long u64T;
using frag8 = __attribute__((ext_vector_type(8))) short;
using f32x4 = __attribute__((ext_vector_type(4))) float;

__device__ __forceinline__ float tanh_fast(float u) {
  float e = __expf(2.0f * u);
  return 1.0f - 2.0f / (e + 1.0f);
}
__device__ __forceinline__ float sigmoid_fast(float u) {
  return 1.0f / (1.0f + __expf(-u));
}
__device__ __forceinline__ ushortT f2bf(float f) {
  unsigned int u = __float_as_uint(f);
  unsigned int r = (u + 0x7FFFu + ((u >> 16) & 1u)) >> 16;
  return (ushortT)r;
}
__device__ __forceinline__ float bf2f(ushortT v) {
  return __uint_as_float(((unsigned int)v) << 16);
}

// ---------- prep: WclsT fp32 [256][4480] and WxT_bf bf16 [128][256] ----------
__global__ __launch_bounds__(256) void trans_kernel(
    const float* __restrict__ Wx, const float* __restrict__ W_cls,
    float* __restrict__ WclsT, ushortT* __restrict__ WxT_bf) {
  int blk = blockIdx.x;
  __shared__ float tile[32][33];
  const int li = threadIdx.x >> 5, lj = threadIdx.x & 31;
  if (blk < 1096) {  // W_cls 4367x256 -> WclsT 256x4480
    int i0 = (blk >> 3) * 32, j0 = (blk & 7) * 32;
#pragma unroll
    for (int k = 0; k < 4; ++k) {
      int i = i0 + li + k * 8;
      if (i < CC) tile[li + k * 8][lj] = W_cls[(size_t)i * 256 + j0 + lj];
    }
    __syncthreads();
#pragma unroll
    for (int k = 0; k < 4; ++k) {
      int j = j0 + li + k * 8, i = i0 + lj;
      if (i < CC) WclsT[(size_t)j * CLS_LD + i] = tile[lj][li + k * 8];
    }
  } else {  // Wx 256x128 -> WxT_bf 128x256
    blk -= 1096;  // 0..31
    int i0 = (blk >> 2) * 32, j0 = (blk & 3) * 32;
#pragma unroll
    for (int k = 0; k < 4; ++k)
      tile[li + k * 8][lj] = Wx[(size_t)(i0 + li + k * 8) * 128 + j0 + lj];
    __syncthreads();
#pragma unroll
    for (int k = 0; k < 4; ++k) {
      int j = j0 + li + k * 8;
      WxT_bf[(size_t)j * 256 + i0 + lj] = f2bf(tile[lj][li + k * 8]);
    }
  }
}

// ---------- xW via MFMA bf16: block = 128 rows of [BT,256] x [256,128] ----------
// Output layout xW[b][t][a] (r13): natural D order, no transpose-bounce.
__global__ __launch_bounds__(256) void xw_mfma(
    const float* __restrict__ x, const ushortT* __restrict__ WxT_bf,
    ushortT* __restrict__ x_bf, ushortT* __restrict__ xW_ta) {
  __shared__ ushortT lds[2 * 128 * 72];  // sX | sW staging; reused as sT[128][136]
#define SX(r, c) lds[(r) * 72 + (c)]
#define SW(r, c) lds[128 * 72 + (r) * 72 + (c)]
#define ST(m, a) lds[(m) * 136 + (a)]
  const int tid = threadIdx.x;
  const int lane = tid & 63, w = tid >> 6;
  const int l15 = lane & 15, quad = lane >> 4;
  const int r0 = blockIdx.x * 128;
  const int row = tid >> 1, half = tid & 1;

  f32x4 acc[2][8];
#pragma unroll
  for (int mt = 0; mt < 2; ++mt)
#pragma unroll
    for (int nt = 0; nt < 8; ++nt) acc[mt][nt] = (f32x4){0.f, 0.f, 0.f, 0.f};

  for (int kk0 = 0; kk0 < 256; kk0 += 64) {
    // stage x (fp32 -> bf16) + write-through to x_bf
    {
      const float4* xp = (const float4*)(x + (size_t)(r0 + row) * DD + kk0 + half * 32);
      uint4 pk[4];
#pragma unroll
      for (int i = 0; i < 4; ++i) {
        float4 f0 = xp[2 * i], f1 = xp[2 * i + 1];
        pk[i].x = (uintT)f2bf(f0.x) | ((uintT)f2bf(f0.y) << 16);
        pk[i].y = (uintT)f2bf(f0.z) | ((uintT)f2bf(f0.w) << 16);
        pk[i].z = (uintT)f2bf(f1.x) | ((uintT)f2bf(f1.y) << 16);
        pk[i].w = (uintT)f2bf(f1.z) | ((uintT)f2bf(f1.w) << 16);
      }
      uint4* sxp = (uint4*)&SX(row, half * 32);
      uint4* gxp = (uint4*)(x_bf + (size_t)(r0 + row) * DD + kk0 + half * 32);
#pragma unroll
      for (int i = 0; i < 4; ++i) { sxp[i] = pk[i]; gxp[i] = pk[i]; }
    }
    // stage WxT_bf slice (n=row)
    {
      const uint4* wp = (const uint4*)(WxT_bf + (size_t)row * DD + kk0 + half * 32);
      uint4* swp = (uint4*)&SW(row, half * 32);
#pragma unroll
      for (int i = 0; i < 4; ++i) swp[i] = wp[i];
    }
    __syncthreads();
#pragma unroll
    for (int kk = 0; kk < 2; ++kk) {
      frag8 a0 = *(const frag8*)&SX(w * 32 + l15, kk * 32 + quad * 8);
      frag8 a1 = *(const frag8*)&SX(w * 32 + 16 + l15, kk * 32 + quad * 8);
#pragma unroll
      for (int nt = 0; nt < 8; ++nt) {
        frag8 bf = *(const frag8*)&SW(nt * 16 + l15, kk * 32 + quad * 8);
        acc[0][nt] = __builtin_amdgcn_mfma_f32_16x16x32_bf16(a0, bf, acc[0][nt], 0, 0, 0);
        acc[1][nt] = __builtin_amdgcn_mfma_f32_16x16x32_bf16(a1, bf, acc[1][nt], 0, 0, 0);
      }
    }
    __syncthreads();
  }
  // natural-order bounce: sT[m][a] = D[m][a], then write xW_ta[(r0+m)][a]
#pragma unroll
  for (int mt = 0; mt < 2; ++mt)
#pragma unroll
    for (int nt = 0; nt < 8; ++nt)
#pragma unroll
      for (int r = 0; r < 4; ++r) {
        int m = w * 32 + mt * 16 + quad * 4 + r;
        int a = nt * 16 + l15;
        ST(m, a) = f2bf(acc[mt][nt][r]);
      }
  __syncthreads();
  {
    const uint4* sp = (const uint4*)&ST(row, half * 64);
    uint4* gp = (uint4*)(xW_ta + (size_t)(r0 + row) * AA + half * 64);
#pragma unroll
    for (int i = 0; i < 8; ++i) gp[i] = sp[i];
  }
#undef SX
#undef SW
#undef ST
}

// ---------- gates v2 (r14-exact): all-3-gates-per-slice + in-block h-combine ----------
__global__ __launch_bounds__(256) void gates_kernel(
    const float* __restrict__ ctx_part, const float* __restrict__ den_part,
    const float* __restrict__ hall_c, const float* __restrict__ W_ih,
    const float* __restrict__ W_hh, const float* __restrict__ b_ih,
    const float* __restrict__ b_hh, const float* __restrict__ Wh,
    float* __restrict__ hall, float* __restrict__ hWh_part, int s) {
  const int sl = blockIdx.x, b = blockIdx.y, tid = threadIdx.x;
  __shared__ __align__(16) float sctx[DD];
  __shared__ float sden;
  __shared__ float sh16[16];
  if (tid < 32) {  // reduce den partials (one wave)
    float d = den_part[b * NCHUNK + tid];
#pragma unroll
    for (int off = 16; off > 0; off >>= 1) d += __shfl_down(d, off, 32);
    if (tid == 0) sden = d;
  }
  {  // reduce ctx partials: coalesced (256 lanes x 32 chunks)
    float acc = 0.f;
#pragma unroll
    for (int c = 0; c < NCHUNK; ++c)
      acc += ctx_part[((size_t)b * NCHUNK + c) * DD + tid];
    sctx[tid] = acc;
  }
  __syncthreads();
  const float invd = 1.0f / sden;
  const int kq = tid & 15, gsub = tid >> 4;  // gsub 0..15 = element within slice
  const float4* cp = (const float4*)sctx + kq * 4;
  const float4* hrow = (s >= 2) ? (const float4*)(hall_c + ((size_t)(s - 2) * BB + b) * HH) + kq * 4 : nullptr;
  float4 c4[4], h4[4];
#pragma unroll
  for (int j = 0; j < 4; ++j) {
    float4 cv = cp[j];
    c4[j].x = cv.x * invd; c4[j].y = cv.y * invd; c4[j].z = cv.z * invd; c4[j].w = cv.w * invd;
    if (hrow) h4[j] = hrow[j];
    else { h4[j].x = 0.f; h4[j].y = 0.f; h4[j].z = 0.f; h4[j].w = 0.f; }
  }
  float gi_g[3], gh_g[3];
#pragma unroll
  for (int it = 0; it < 3; ++it) {
    const int g = it * 256 + sl * 16 + gsub;
    const float4* wi = (const float4*)(W_ih + (size_t)g * DD) + kq * 4;
    const float4* wh = (const float4*)(W_hh + (size_t)g * HH) + kq * 4;
    float gi = 0.f, gh = 0.f;
#pragma unroll
    for (int j = 0; j < 4; ++j) {
      float4 wv = wi[j];
      gi += c4[j].x * wv.x + c4[j].y * wv.y + c4[j].z * wv.z + c4[j].w * wv.w;
      wv = wh[j];
      gh += h4[j].x * wv.x + h4[j].y * wv.y + h4[j].z * wv.z + h4[j].w * wv.w;
    }
#pragma unroll
    for (int off = 8; off > 0; off >>= 1) {
      gi += __shfl_down(gi, off, 16);
      gh += __shfl_down(gh, off, 16);
    }
    gi_g[it] = gi + b_ih[g];  // valid on kq==0 lane (the only consumer)
    gh_g[it] = gh + b_hh[g];
  }
  if (kq == 0) {  // h-combine for element i = sl*16 + gsub, fully in registers
    const int i = sl * 16 + gsub;
    float hp = (s >= 2) ? hall_c[((size_t)(s - 2) * BB + b) * HH + i] : 0.f;
    float r = sigmoid_fast(gi_g[0] + gh_g[0]);
    float z = sigmoid_fast(gi_g[1] + gh_g[1]);
    float n = tanh_fast(gi_g[2] + r * gh_g[2]);
    float hv = (1.f - z) * n + z * hp;
    hall[((size_t)(s - 1) * BB + b) * HH + i] = hv;
    sh16[gsub] = hv;
  }
  __syncthreads();
  if (tid < AA) {  // partial hWh over this block's 16 k's (coalesced Wh rows)
    float acc = 0.f;
#pragma unroll
    for (int k = 0; k < 16; ++k)
      acc = fmaf(sh16[k], Wh[(size_t)(sl * 16 + k) * AA + tid], acc);
    hWh_part[((size_t)b * 16 + sl) * AA + tid] = acc;
  }
}

// ---------- per-step attention. grid (32 b, 32 chunks), 256 thr ----------
// CHANGE vs r14 (single A/B variable): x prefetch uses PLAIN loads — the
// nontemporal hint is removed. Theory: nt early-evicts/bypasses the 256 MB
// Infinity Cache, forcing the 33.5 MB/step x re-read to HBM (~5.3 us) instead
// of L3 (~2 us). x can never be L2-resident anyway (4.2 MB/XCD > 4 MB L2), so
// nt's only effect on this stream is the L3 behavior.
__global__ __launch_bounds__(256, 4) void att_kernel(
    const ushortT* __restrict__ x_bf, const ushortT* __restrict__ xW_ta,
    const float* __restrict__ hWh_part, const float* __restrict__ v,
    float* __restrict__ ctx_part, float* __restrict__ den_part) {
  const int tid = threadIdx.x;
  const int b = blockIdx.x;
  const int chunk = blockIdx.y;  // 0..31, 64 t's each
  const int t0 = chunk * 64;
  __shared__ float sh_hWh[AA], sh_v[AA];
  __shared__ float sh_w[64];
  __shared__ __align__(16) float sh_ctx[4 * DD];
  if (tid < AA) {
    float hw = 0.f;
    if (hWh_part) {
#pragma unroll
      for (int sl = 0; sl < 16; ++sl)
        hw += hWh_part[((size_t)b * 16 + sl) * AA + tid];
    }
    sh_hWh[tid] = hw;
    sh_v[tid] = v[tid];
  }
  __syncthreads();  // waits only the 128-lane LDS stores above
  // x prefetch issues HERE: overlaps with all of Phase A (r11 win)
  const int j4 = tid >> 6, dq = tid & 63;
  u64T xr[16];
  {
    const u64T* xb4 = (const u64T*)x_bf;
#pragma unroll
    for (int j = 0; j < 16; ++j)
      xr[j] = xb4[(((size_t)(b * TT + t0 + j * 4 + j4)) * DD >> 2) + dq];
  }
  // Phase A: scores. thread = (tl = tid>>2 in [0,64), aseg = tid&3 owns 32 a's)
  {
    const int tl = tid >> 2, aseg = tid & 3;
    const uint4* xw16 = (const uint4*)(xW_ta + (size_t)(b * TT + t0 + tl) * AA + aseg * 32);
    float e = 0.f;
#pragma unroll
    for (int i = 0; i < 4; ++i) {
      uint4 u = xw16[i];
      const int ab = aseg * 32 + i * 8;
      e = fmaf(tanh_fast(bf2f((ushortT)(u.x & 0xFFFFu)) + sh_hWh[ab + 0]), sh_v[ab + 0], e);
      e = fmaf(tanh_fast(bf2f((ushortT)(u.x >> 16)) + sh_hWh[ab + 1]), sh_v[ab + 1], e);
      e = fmaf(tanh_fast(bf2f((ushortT)(u.y & 0xFFFFu)) + sh_hWh[ab + 2]), sh_v[ab + 2], e);
      e = fmaf(tanh_fast(bf2f((ushortT)(u.y >> 16)) + sh_hWh[ab + 3]), sh_v[ab + 3], e);
      e = fmaf(tanh_fast(bf2f((ushortT)(u.z & 0xFFFFu)) + sh_hWh[ab + 4]), sh_v[ab + 4], e);
      e = fmaf(tanh_fast(bf2f((ushortT)(u.z >> 16)) + sh_hWh[ab + 5]), sh_v[ab + 5], e);
      e = fmaf(tanh_fast(bf2f((ushortT)(u.w & 0xFFFFu)) + sh_hWh[ab + 6]), sh_v[ab + 6], e);
      e = fmaf(tanh_fast(bf2f((ushortT)(u.w >> 16)) + sh_hWh[ab + 7]), sh_v[ab + 7], e);
    }
    e += __shfl_xor(e, 1, 4);
    e += __shfl_xor(e, 2, 4);
    if (aseg == 0) sh_w[tl] = __expf(e);  // |e| <= ||v||_1 ~ 5: safe, no max-pass
  }
  __syncthreads();
  // Phase B: ctx partials from prefetched regs (unpack u64 -> 4 bf16)
  {
    float4 acc = {0.f, 0.f, 0.f, 0.f};
#pragma unroll
    for (int j = 0; j < 16; ++j) {
      float w = sh_w[j * 4 + j4];
      u64T u = xr[j];
      acc.x = fmaf(w, bf2f((ushortT)(u       & 0xFFFFu)), acc.x);
      acc.y = fmaf(w, bf2f((ushortT)((u >> 16) & 0xFFFFu)), acc.y);
      acc.z = fmaf(w, bf2f((ushortT)((u >> 32) & 0xFFFFu)), acc.z);
      acc.w = fmaf(w, bf2f((ushortT)((u >> 48) & 0xFFFFu)), acc.w);
    }
    ((float4*)sh_ctx)[j4 * 64 + dq] = acc;
  }
  __syncthreads();
  {
    float sum = sh_ctx[tid] + sh_ctx[DD + tid] + sh_ctx[2 * DD + tid] + sh_ctx[3 * DD + tid];
    ctx_part[((size_t)b * NCHUNK + chunk) * DD + tid] = sum;  // plain coalesced store
  }
  if (tid < 64) {
    float ds = sh_w[tid];
#pragma unroll
    for (int off = 32; off > 0; off >>= 1) ds += __shfl_down(ds, off, 64);
    if (tid == 0) den_part[b * NCHUNK + chunk] = ds;
  }
}

// ---------- final: out[b,s,c] = hall[s,b,:] @ W_cls^T + b_cls ----------
// r1-EXACT (measured 45.0 us — best of 5 variants; cls frozen).
__global__ __launch_bounds__(256) void cls_kernel(
    const float* __restrict__ hall, const float* __restrict__ WclsT,
    const float* __restrict__ b_cls, float* __restrict__ out) {
  const int tid = threadIdx.x;
  const int c0 = blockIdx.x * 128;
  const int r0 = blockIdx.y * 32;
  const int cq = tid & 31, rg = tid >> 5;
  const int c = c0 + cq * 4;
  __shared__ __align__(16) float shh[32 * HH];
  {
    const float4* hsrc = (const float4*)(hall + (size_t)r0 * HH);
    float4* hdst = (float4*)shh;
#pragma unroll
    for (int i = 0; i < 8; ++i) hdst[tid + 256 * i] = hsrc[tid + 256 * i];
  }
  __syncthreads();
  float acc[4][4];
#pragma unroll
  for (int j = 0; j < 4; ++j)
#pragma unroll
    for (int l = 0; l < 4; ++l) acc[j][l] = 0.f;
#pragma unroll 4
  for (int k = 0; k < HH; ++k) {
    float4 w4 = *(const float4*)(WclsT + (size_t)k * CLS_LD + c);
    float h0 = shh[(rg * 4 + 0) * HH + k];
    float h1 = shh[(rg * 4 + 1) * HH + k];
    float h2 = shh[(rg * 4 + 2) * HH + k];
    float h3 = shh[(rg * 4 + 3) * HH + k];
    acc[0][0] = fmaf(h0, w4.x, acc[0][0]); acc[0][1] = fmaf(h0, w4.y, acc[0][1]);
    acc[0][2] = fmaf(h0, w4.z, acc[0][2]); acc[0][3] = fmaf(h0, w4.w, acc[0][3]);
    acc[1][0] = fmaf(h1, w4.x, acc[1][0]); acc[1][1] = fmaf(h1, w4.y, acc[1][1]);
    acc[1][2] = fmaf(h1, w4.z, acc[1][2]); acc[1][3] = fmaf(h1, w4.w, acc[1][3]);
    acc[2][0] = fmaf(h2, w4.x, acc[2][0]); acc[2][1] = fmaf(h2, w4.y, acc[2][1]);
    acc[2][2] = fmaf(h2, w4.z, acc[2][2]); acc[2][3] = fmaf(h2, w4.w, acc[2][3]);
    acc[3][0] = fmaf(h3, w4.x, acc[3][0]); acc[3][1] = fmaf(h3, w4.y, acc[3][1]);
    acc[3][2] = fmaf(h3, w4.z, acc[3][2]); acc[3][3] = fmaf(h3, w4.w, acc[3][3]);
  }
#pragma unroll
  for (int j = 0; j < 4; ++j) {
    int row = r0 + rg * 4 + j;  // row = s*BB + b
    int bb = row & (BB - 1), st = row >> 5;
    size_t obase = ((size_t)bb * NSTEPS + st) * CC;
#pragma unroll
    for (int l = 0; l < 4; ++l) {
      int cc = c + l;
      if (cc < CC) out[obase + cc] = acc[j][l] + b_cls[cc];
    }
  }
}

extern "C" void kernel_launch(void* const* d_in, const int* in_sizes, int n_in,
                              void* d_out, int out_size, void* d_ws, size_t ws_size,
                              hipStream_t stream) {
  const float* x     = (const float*)d_in[0];
  const float* Wx    = (const float*)d_in[1];
  const float* Wh    = (const float*)d_in[2];
  const float* v     = (const float*)d_in[3];
  const float* W_ih  = (const float*)d_in[4];
  const float* W_hh  = (const float*)d_in[5];
  const float* b_ih  = (const float*)d_in[6];
  const float* b_hh  = (const float*)d_in[7];
  const float* W_cls = (const float*)d_in[8];
  const float* b_cls = (const float*)d_in[9];
  float* out = (float*)d_out;

  // workspace
  float* ctx_part = (float*)d_ws;                           // 32*32*256
  float* den_part = ctx_part + (size_t)BB * NCHUNK * DD;    // 32*32
  float* hWh_part = den_part + BB * NCHUNK;                 // 32*16*128
  float* hall     = hWh_part + (size_t)BB * 16 * AA;        // 22*32*256
  float* WclsT    = hall + (size_t)NSTEPS * BB * HH;        // 256*4480
  ushortT* WxT_bf = (ushortT*)(WclsT + (size_t)256 * CLS_LD);  // 128*256
  ushortT* x_bf   = WxT_bf + 128 * 256;                     // BT*256
  ushortT* xW_ta  = x_bf + (size_t)BB * TT * DD;            // B*T*A

  trans_kernel<<<1096 + 32, 256, 0, stream>>>(Wx, W_cls, WclsT, WxT_bf);
  xw_mfma<<<(BB * TT) / 128, 256, 0, stream>>>(x, WxT_bf, x_bf, xW_ta);

  att_kernel<<<dim3(BB, NCHUNK), 256, 0, stream>>>(x_bf, xW_ta, nullptr, v, ctx_part, den_part);
  for (int s = 1; s <= NSTEPS; ++s) {
    gates_kernel<<<dim3(16, BB), 256, 0, stream>>>(ctx_part, den_part, hall, W_ih, W_hh,
                                                   b_ih, b_hh, Wh, hall, hWh_part, s);
    if (s < NSTEPS)
      att_kernel<<<dim3(BB, NCHUNK), 256, 0, stream>>>(x_bf, xW_ta, hWh_part, v, ctx_part, den_part);
  }
  cls_kernel<<<dim3(35, 22), 256, 0, stream>>>(hall, WclsT, b_cls, out);
}